// Round 11
// baseline (314.677 us; speedup 1.0000x reference)
//
#include <hip/hip_runtime.h>
#include <cstdint>

// Problem constants
#define NB 32
#define IC 256
#define OC 256
#define H 56
#define WIDTH 56
#define OH 54
#define OW 54
#define HW (H*WIDTH)          // 3136
#define OHW (OH*OW)           // 2916
#define KTOT 2304             // 9 * 256, k = (kh*3+kw)*256 + c
#define M_TOT (NB*OHW)        // 93312
#define C8N (IC/8)            // 32 chunks of 8 channels

// GEMM tiling
#define BM 96                 // 93312/96 = 972 blocks -> 95% packing @2 blocks/CU
#define BO 256                // out-channel tile (= all of OC)
#define BK 32
#define KSTEPS (KTOT/BK)      // 72
#define MBLOCKS (M_TOT/BM)    // 972
#define XBLK ((NB*C8N*HW)/256)  // 12544 xform blocks
#define WPAD 1024             // pad W buf to 18 KB: 3 bufs = 54 KB pins 2 blk/CU

// weights pre-tiled as per-K-step LDS images WITH chunk swizzle:
// g_qwt[step][r][cs][b] = sign(W[o=r][k = step*32 + (cs ^ ((r>>1)&3))*8 + b])
__device__ __align__(16) unsigned short g_qwt[KSTEPS*BO*BK];
// x as [n][c8][hw][8] bf16 (16B granule = 8 consecutive channels at one pixel)
__device__ __align__(16) unsigned short g_xq[NB*C8N*HW*8];

typedef __bf16 bf16x8 __attribute__((ext_vector_type(8)));
typedef float  f32x4  __attribute__((ext_vector_type(4)));

typedef __attribute__((address_space(1))) const unsigned int gas_u32;
typedef __attribute__((address_space(3))) unsigned int las_u32;
__device__ __forceinline__ void async_copy16(const void* g, void* l) {
  __builtin_amdgcn_global_load_lds((gas_u32*)g, (las_u32*)l, 16, 0, 0);
}

__device__ inline unsigned short f32_bf16(float f) {
  union { float f; unsigned int u; } v; v.f = f;
  unsigned int u = v.u;
  return (unsigned short)((u + 0x7FFFu + ((u >> 16) & 1u)) >> 16);  // RNE
}

#define WAITV(N) asm volatile("s_waitcnt vmcnt(" #N ")" ::: "memory")
#define SCHEDB() __builtin_amdgcn_sched_barrier(0)
#define BARRIER() do { SCHEDB(); __builtin_amdgcn_s_barrier(); SCHEDB(); } while (0)

// ---- Kernel 1: fused prep (x transform + weight repack), one launch ------
__global__ __launch_bounds__(256) void prep(const float* __restrict__ x,
                                            const float* __restrict__ w) {
  const int t = threadIdx.x;
  if (blockIdx.x < XBLK) {
    int g = blockIdx.x * 256 + t;                   // granule id, < 3211264
    int hw = g % HW;
    int tc = g / HW;                                // n*32 + c8
    int c8 = tc & 31;
    int n  = tc >> 5;
    const float* src = x + (n*IC + c8*8)*HW + hw;
    unsigned int o[4];
    #pragma unroll
    for (int j = 0; j < 4; ++j) {
      unsigned int lo = f32_bf16(src[(2*j+0)*HW]);
      unsigned int hi = f32_bf16(src[(2*j+1)*HW]);
      o[j] = lo | (hi << 16);
    }
    *(uint4*)(&g_xq[g*8]) = *(uint4*)o;
  } else {
    int L = (blockIdx.x - XBLK) * 256 + t;          // < 589824
    int step = L >> 13;
    int r    = (L >> 5) & 255;
    int kc   = L & 31;
    int cs   = kc >> 3;
    int b    = kc & 7;
    int csrc = cs ^ ((r >> 1) & 3);                 // bank-conflict swizzle
    int k    = step*BK + csrc*8 + b;
    int pos  = k >> 8;
    int c    = k & 255;
    float v = w[r*2304 + c*9 + pos];
    g_qwt[L] = (v > 0.f) ? 0x3F80u : ((v < 0.f) ? 0xBF80u : 0u);
  }
}

// ---- Kernel 2: implicit-GEMM binary conv, 256o x 96m tile ----------------
// 8 waves (4o x 2m of 64x48), 16x16x32 MFMA. W via 3-deep LDS ring (only
// conflict-free fragment pattern at BK=32 -- measured r4/r5). X is NOT
// staged in LDS: each lane's B-fragment is one contiguous 16B granule of
// g_xq -> direct global->VGPR loads, double-buffered (xa/xb named sets,
// static indexing). Cuts LDS traffic 78->48 KB/block-step and removes X
// from the barrier-critical path.
// ONE barrier per phase. Correctness ledger (in-order vmcnt retirement):
// phase p issues STAGE_W(p+3) THEN LOADX(p+2) (sched_barrier-pinned order),
// so the compiler's wait on X(p) before COMPUTE(p) also guarantees W(p+1)'s
// DMA retired; the phase barrier after COMPUTE(p) publishes it block-wide.
// REGISTER WALL (r7): never force occupancy via launch_bounds min-waves;
// (512,2) = 256-reg budget, no spill pressure. LDS 54 KB pins 2 blocks/CU.
__global__ __launch_bounds__(512, 2) void bconv_gemm(float* __restrict__ out) {
  __shared__ __align__(16) unsigned short Wl[3][BO*BK + WPAD];  // 3 x 18 KB
  const int t = threadIdx.x;

  // XCD-aware bijective remap: 972 = 8*121 + 4 (q=121, r=4).
  const int orig = blockIdx.x;
  const int xcd  = orig & 7;
  const int idx  = orig >> 3;
  const int base = (xcd < 4) ? xcd*122 : (4*122 + (xcd - 4)*121);
  const int m0   = (base + idx) * BM;

  const int lane = t & 63;
  const int wv   = t >> 6;                          // 0..7
  const int col  = lane & 15;
  const int quad = lane >> 4;
  const int wo   = (wv >> 1) * 64;                  // wave o-offset (0,64,128,192)
  const int wm   = (wv & 1) * 48;                   // wave m-offset (0,48)
  // W read-side swizzle: rows (multiple of 16)+col -> ((row>>1)&3)==((col>>1)&3)
  const int sw   = (quad ^ ((col >> 1) & 3)) * 8;
  int aoff[4];
  #pragma unroll
  for (int i = 0; i < 4; ++i)
    aoff[i] = (wo + i*16 + col)*BK + sw;

  // Per-lane X pixel bases for the 3 B-fragments (quad folded in):
  // addr(step) = pbq[i] + sA(step), sA = (((step*4)&31)*HW + kh*WIDTH + kw)*8
  int pbq0, pbq1, pbq2;
  {
    int pb[3];
    #pragma unroll
    for (int i = 0; i < 3; ++i) {
      int m  = m0 + wm + i*16 + col;
      int n  = m / OHW;
      int rm = m - n*OHW;
      int oh = rm / OW;
      int ow = rm - oh*OW;
      pb[i] = ((n*C8N + quad)*HW + oh*WIDTH + ow) * 8;
    }
    pbq0 = pb[0]; pbq1 = pb[1]; pbq2 = pb[2];
  }

  f32x4 acc[4][3];
  #pragma unroll
  for (int a = 0; a < 4; ++a)
    #pragma unroll
    for (int b = 0; b < 3; ++b)
      acc[a][b] = (f32x4){0.f, 0.f, 0.f, 0.f};

  bf16x8 xa0, xa1, xa2, xb0, xb1, xb2;   // two named X-fragment sets

#define STAGE_W(step, WBUF) do { \
    const unsigned short* ws_ = g_qwt + (step)*(BO*BK); \
    async_copy16(&ws_[t*8],       &WBUF[t*8]); \
    async_copy16(&ws_[(t+512)*8], &WBUF[(t+512)*8]); \
  } while (0)

#define LOADX(step, X0, X1, X2) do { \
    int pos_ = (step) >> 3; \
    int kh_  = pos_ / 3; \
    int kw_  = pos_ - 3*kh_; \
    int sA_  = ((((step)*4) & 31)*HW + kh_*WIDTH + kw_) * 8; \
    X0 = *(const bf16x8*)(&g_xq[pbq0 + sA_]); \
    X1 = *(const bf16x8*)(&g_xq[pbq1 + sA_]); \
    X2 = *(const bf16x8*)(&g_xq[pbq2 + sA_]); \
  } while (0)

#define COMPUTEM(WB, X0, X1, X2) do { \
    bf16x8 av_[4]; \
    _Pragma("unroll") \
    for (int i = 0; i < 4; ++i) av_[i] = *(const bf16x8*)(&WB[aoff[i]]); \
    __builtin_amdgcn_s_setprio(1); \
    _Pragma("unroll") \
    for (int io = 0; io < 4; ++io) { \
      acc[io][0] = __builtin_amdgcn_mfma_f32_16x16x32_bf16(av_[io], X0, acc[io][0], 0, 0, 0); \
      acc[io][1] = __builtin_amdgcn_mfma_f32_16x16x32_bf16(av_[io], X1, acc[io][1], 0, 0, 0); \
      acc[io][2] = __builtin_amdgcn_mfma_f32_16x16x32_bf16(av_[io], X2, acc[io][2], 0, 0, 0); \
    } \
    __builtin_amdgcn_s_setprio(0); \
  } while (0)

  // One phase: COMPUTE(p); BAR; STAGE_W(p+3 -> Wl[p%3]); LOADX(p+2 -> set p&1)
#define PHASE(p_, WB, CX0, CX1, CX2) do { \
    COMPUTEM(WB, CX0, CX1, CX2); \
    BARRIER(); \
    STAGE_W((p_) + 3, WB); \
    SCHEDB(); \
    LOADX((p_) + 2, CX0, CX1, CX2); \
    SCHEDB(); \
  } while (0)

  // Prologue. Issue order (FIFO): W0(2), W1(2), X0(3), W2(2), X1(3) = 12.
  STAGE_W(0, Wl[0]);
  STAGE_W(1, Wl[1]);
  SCHEDB();
  LOADX(0, xa0, xa1, xa2);
  SCHEDB();
  STAGE_W(2, Wl[2]);
  SCHEDB();
  LOADX(1, xb0, xb1, xb2);
  SCHEDB();
  WAITV(10);           // W0 retired (10 younger ops may remain)
  BARRIER();           // W0 visible block-wide

  // Main loop: phases 0..65 (11 iters x 6: lcm of ring 3 and X parity 2).
  #pragma unroll 1
  for (int s = 0; s < 66; s += 6) {
    PHASE(s + 0, Wl[0], xa0, xa1, xa2);
    PHASE(s + 1, Wl[1], xb0, xb1, xb2);
    PHASE(s + 2, Wl[2], xa0, xa1, xa2);
    PHASE(s + 3, Wl[0], xb0, xb1, xb2);
    PHASE(s + 4, Wl[1], xa0, xa1, xa2);
    PHASE(s + 5, Wl[2], xb0, xb1, xb2);
  }

  // Tail: phases 66..71 (stage W up to 71, load X up to 71, then drain).
  PHASE(66, Wl[0], xa0, xa1, xa2);        // stages W69, loads X68
  PHASE(67, Wl[1], xb0, xb1, xb2);        // stages W70, loads X69
  PHASE(68, Wl[2], xa0, xa1, xa2);        // stages W71, loads X70
  COMPUTEM(Wl[0], xb0, xb1, xb2);         // tile 69
  BARRIER();
  LOADX(71, xb0, xb1, xb2);
  SCHEDB();
  COMPUTEM(Wl[1], xa0, xa1, xa2);         // tile 70
  BARRIER();                              // publish W71 (retired via X70 wait)
  COMPUTEM(Wl[2], xb0, xb1, xb2);         // tile 71

#undef PHASE
#undef COMPUTEM
#undef LOADX
#undef STAGE_W

  // Epilogue: D col=(lane&15)->m, row=(quad*4+r)->o. out[n][o][oh][ow].
  #pragma unroll
  for (int im = 0; im < 3; ++im) {
    int m  = m0 + wm + im*16 + col;
    int n  = m / OHW;
    int rm = m - n*OHW;
    float* obase = out + n*(OC*OHW) + rm;
    #pragma unroll
    for (int io = 0; io < 4; ++io) {
      int orow = wo + io*16 + quad*4;
      #pragma unroll
      for (int r = 0; r < 4; ++r)
        obase[(orow + r)*OHW] = acc[io][im][r];
    }
  }
}

extern "C" void kernel_launch(void* const* d_in, const int* in_sizes, int n_in,
                              void* d_out, int out_size, void* d_ws, size_t ws_size,
                              hipStream_t stream) {
  const float* x = (const float*)d_in[0];   // [32,256,56,56] fp32
  const float* w = (const float*)d_in[1];   // [256,256,3,3] fp32
  float* out = (float*)d_out;               // [32,256,54,54] fp32

  prep<<<dim3(XBLK + (KSTEPS*BO*BK)/256), 256, 0, stream>>>(x, w);  // 14848 blocks
  bconv_gemm<<<dim3(MBLOCKS), 512, 0, stream>>>(out);               // 972 blocks
}